// Round 9
// baseline (1179.352 us; speedup 1.0000x reference)
//
#include <hip/hip_runtime.h>
#include <hip/hip_bf16.h>

// Sizes (fixed by the reference)
#define T_TOKENS 1024
#define HID      2048
#define NEXP     64
#define TOPK     8
#define MLP      768
#define NPAIR    (T_TOKENS * TOPK)   // 8192

typedef __bf16 bf16x8 __attribute__((ext_vector_type(8)));
typedef float  f32x4  __attribute__((ext_vector_type(4)));
typedef unsigned int u32x2 __attribute__((ext_vector_type(2)));
typedef unsigned int u32x4 __attribute__((ext_vector_type(4)));

#define LDK 40   // LDS row stride in shorts (16B-aligned b128 frag reads, 2-way-max bank aliasing)

static __device__ __forceinline__ unsigned short f2bf(float f) {
    __hip_bfloat16 h = __float2bfloat16(f);
    unsigned short u;
    __builtin_memcpy(&u, &h, sizeof(u));
    return u;
}
static __device__ __forceinline__ unsigned int pk2bf(float a, float b) {
    return (unsigned int)f2bf(a) | ((unsigned int)f2bf(b) << 16);
}

// ---------------------------------------------------------------------------
// Router: logits = hs @ router_w, top-8, softmax over the 8.  Each wave also
// converts its token row fp32->bf16 into xb (cvt kernel folded in).
// ---------------------------------------------------------------------------
__global__ __launch_bounds__(256) void router_topk_kernel(
    const float* __restrict__ hs, const float* __restrict__ rw,
    int* __restrict__ sel, float* __restrict__ wts, unsigned short* __restrict__ xb)
{
    const int lane = threadIdx.x & 63;
    const int tg   = threadIdx.x >> 6;
    const int t    = blockIdx.x * 4 + tg;

    // fold-in: convert this token's row to bf16
    {
        const float* xr = hs + (size_t)t * HID;
        unsigned short* xw = xb + (size_t)t * HID;
        #pragma unroll
        for (int c = 0; c < 4; ++c) {
            int i = (lane + c * 64) * 8;
            f32x4 a = *(const f32x4*)(xr + i);
            f32x4 b = *(const f32x4*)(xr + i + 4);
            u32x4 v;
            v[0] = pk2bf(a[0], a[1]); v[1] = pk2bf(a[2], a[3]);
            v[2] = pk2bf(b[0], b[1]); v[3] = pk2bf(b[2], b[3]);
            *(u32x4*)(xw + i) = v;
        }
    }

    const float4* x4 = (const float4*)(hs + (size_t)t * HID);
    float acc = 0.f;
    for (int h4 = 0; h4 < HID / 4; ++h4) {
        float4 xv = x4[h4];
        int hb = h4 * 4 * NEXP + lane;
        acc += xv.x * rw[hb] + xv.y * rw[hb + NEXP]
             + xv.z * rw[hb + 2 * NEXP] + xv.w * rw[hb + 3 * NEXP];
    }

    float v = acc;
    float tv[TOPK]; int ti[TOPK];
    for (int i = 0; i < TOPK; ++i) {
        float m = v; int mi = lane;
        for (int off = 32; off > 0; off >>= 1) {
            float om  = __shfl_xor(m, off, 64);
            int   omi = __shfl_xor(mi, off, 64);
            if (om > m || (om == m && omi < mi)) { m = om; mi = omi; }
        }
        tv[i] = m; ti[i] = mi;
        if (lane == mi) v = -__builtin_inff();
    }
    if (lane == 0) {
        float mx = tv[0], s = 0.f, e[TOPK];
        for (int i = 0; i < TOPK; ++i) { e[i] = __expf(tv[i] - mx); s += e[i]; }
        float inv = 1.f / s;
        for (int i = 0; i < TOPK; ++i) {
            wts[t * TOPK + i] = e[i] * inv;
            sel[t * TOPK + i] = ti[i];
        }
    }
}

// ---------------------------------------------------------------------------
// Routing bookkeeping: count + scan + scatter in ONE kernel (1 block, LDS).
// ---------------------------------------------------------------------------
__global__ __launch_bounds__(1024) void route_kernel(
    const int* __restrict__ sel, int* __restrict__ offsets, int* __restrict__ rows)
{
    __shared__ int cnt[NEXP];
    __shared__ int cur[NEXP];
    const int t = threadIdx.x;
    if (t < NEXP) cnt[t] = 0;
    __syncthreads();
    int e[8];
    const int p0 = t * 8;
    #pragma unroll
    for (int j = 0; j < 8; ++j) {
        e[j] = sel[p0 + j];
        atomicAdd(&cnt[e[j]], 1);
    }
    __syncthreads();
    if (t == 0) {
        int s = 0;
        for (int i = 0; i < NEXP; ++i) { cur[i] = s; offsets[i] = s; s += cnt[i]; }
        offsets[NEXP] = s;
    }
    __syncthreads();
    #pragma unroll
    for (int j = 0; j < 8; ++j) {
        int pos = atomicAdd(&cur[e[j]], 1);
        rows[pos] = p0 + j;   // pair id; token = p>>3
    }
}

// ---------------------------------------------------------------------------
// gate/up GEMM + SiLU fused.  EXACT best-known kernel (272-276 us, R2/R5/R8).
// Block = 512 threads = 8 waves.  Waves 0-3: gate, waves 4-7: up, each
// 48 rows x 64 cols.  A bf16 from xb via LDS; W E/O register double-buffer;
// raw s_barrier + lgkmcnt(0) only (vmcnt stays counted in the main loop).
// FROZEN — do not perturb (4 redesigns all measured worse).
// ---------------------------------------------------------------------------
__global__ __launch_bounds__(512) void gateup_kernel(
    const unsigned short* __restrict__ xb, const float* __restrict__ gw,
    const float* __restrict__ uw, const int* __restrict__ offsets,
    const int* __restrict__ rows, unsigned short* __restrict__ hb)
{
    // bijective XCD swizzle (768 = 8 * 96): each XCD gets 8 whole experts
    const int bid = blockIdx.x;
    const int sw  = (bid & 7) * 96 + (bid >> 3);
    const int e   = sw / 12;
    const int n0  = (sw % 12) * 64;

    const int r0 = offsets[e];
    const int nrows = offsets[e + 1] - r0;
    if (nrows <= 0) return;

    // 2 buffers x (A 192*40 + G 64*40 + U 64*40) shorts = 51200 B
    __shared__ __align__(16) float smemf[12800];
    unsigned short* smem = (unsigned short*)smemf;

    const int thr  = threadIdx.x;
    const int wave = thr >> 6;
    const int lane = thr & 63;
    const int wg   = wave & 3;          // row-group 0..3 (48 rows each)
    const int isUp = wave >> 2;         // waves 4-7 do up
    const int fr   = lane & 15;
    const int fq   = lane >> 4;

    // A staging: u32x2 (4 bf16) per slot; rows ar, ar+64, ar+128
    const int ar = thr >> 3;            // row 0..63
    const int ac = (thr & 7) * 4;       // k-col in shorts (0,4,..,28)

    // W staging: thr<256 -> gate, thr>=256 -> up; pair-slot = (k2, nq)
    const int wk2 = thr & 15;           // k = 2*wk2
    const int wnq = (thr & 255) >> 4;   // n = wnq*4
    const float* wsrc = (thr >= 256 ? uw : gw)
        + (size_t)e * HID * MLP + (size_t)(2 * wk2) * MLP + n0 + wnq * 4;
    const int mofs = (thr >= 256) ? 10240 : 7680;  // U / G region

    const int NS = HID / 32;            // 64 K-steps (even)

    for (int m0 = 0; m0 < nrows; m0 += 192) {
        // ---- hoist gather pointers (rows[] read once per m-pass)
        const unsigned short *ap0, *ap1, *ap2;
        bool av0, av1, av2;
        {
            int gr0 = m0 + ar, gr1 = m0 + ar + 64, gr2 = m0 + ar + 128;
            av0 = gr0 < nrows; av1 = gr1 < nrows; av2 = gr2 < nrows;
            int p0 = av0 ? rows[r0 + gr0] : 0;
            int p1 = av1 ? rows[r0 + gr1] : 0;
            int p2 = av2 ? rows[r0 + gr2] : 0;
            ap0 = xb + (size_t)(p0 >> 3) * HID + ac;
            ap1 = xb + (size_t)(p1 >> 3) * HID + ac;
            ap2 = xb + (size_t)(p2 >> 3) * HID + ac;
        }

        u32x2 va0, va1, va2;
        f32x4 w0e, w1e, w0o, w1o;
        const u32x2 z2 = (u32x2){0u, 0u};
        const f32x4 fz = (f32x4){0.f, 0.f, 0.f, 0.f};

        auto LOAD_A = [&](int s) {
            va0 = av0 ? *(const u32x2*)(ap0 + s * 32) : z2;
            va1 = av1 ? *(const u32x2*)(ap1 + s * 32) : z2;
            va2 = av2 ? *(const u32x2*)(ap2 + s * 32) : z2;
        };
        auto WRITE_A = [&](int s) {
            unsigned short* b = smem + (s & 1) * 12800;
            *(u32x2*)(b + ar * LDK + ac) = va0;
            *(u32x2*)(b + (ar + 64) * LDK + ac) = va1;
            *(u32x2*)(b + (ar + 128) * LDK + ac) = va2;
        };
        auto LOAD_WE = [&](int s) {
            const float* wp = wsrc + (size_t)s * 32 * MLP;
            w0e = *(const f32x4*)wp;  w1e = *(const f32x4*)(wp + MLP);
        };
        auto LOAD_WO = [&](int s) {
            const float* wp = wsrc + (size_t)s * 32 * MLP;
            w0o = *(const f32x4*)wp;  w1o = *(const f32x4*)(wp + MLP);
        };
        auto WRITE_WE = [&](int s) {
            unsigned short* wb = smem + (s & 1) * 12800 + mofs;
            #pragma unroll
            for (int i = 0; i < 4; ++i)
                *(unsigned int*)(wb + (wnq * 4 + i) * LDK + 2 * wk2) = pk2bf(w0e[i], w1e[i]);
        };
        auto WRITE_WO = [&](int s) {
            unsigned short* wb = smem + (s & 1) * 12800 + mofs;
            #pragma unroll
            for (int i = 0; i < 4; ++i)
                *(unsigned int*)(wb + (wnq * 4 + i) * LDK + 2 * wk2) = pk2bf(w0o[i], w1o[i]);
        };

        f32x4 acc[3][4];
        #pragma unroll
        for (int ms = 0; ms < 3; ++ms)
            #pragma unroll
            for (int ns = 0; ns < 4; ++ns) acc[ms][ns] = fz;

        const int rem = nrows - m0 - wg * 48;

        // prologue
        LOAD_WE(0);
        LOAD_WO(1);
        LOAD_A(0);
        WRITE_WE(0);
        WRITE_A(0);
        LOAD_A(1);
        asm volatile("s_waitcnt lgkmcnt(0)" ::: "memory");
        __builtin_amdgcn_s_barrier();

        #define GU_MFMA(BB)                                                          \
        {                                                                            \
            const unsigned short* wbb = (BB) + mofs;                                 \
            bf16x8 aF0, aF1, aF2, wF0, wF1, wF2, wF3;                                \
            wF0 = *(const bf16x8*)(wbb + (0 * 16 + fr) * LDK + fq * 8);              \
            wF1 = *(const bf16x8*)(wbb + (1 * 16 + fr) * LDK + fq * 8);              \
            wF2 = *(const bf16x8*)(wbb + (2 * 16 + fr) * LDK + fq * 8);              \
            wF3 = *(const bf16x8*)(wbb + (3 * 16 + fr) * LDK + fq * 8);              \
            aF0 = *(const bf16x8*)((BB) + (wg * 48 + fr) * LDK + fq * 8);            \
            aF1 = *(const bf16x8*)((BB) + (wg * 48 + 16 + fr) * LDK + fq * 8);       \
            aF2 = *(const bf16x8*)((BB) + (wg * 48 + 32 + fr) * LDK + fq * 8);       \
            if (rem > 0) {                                                           \
                acc[0][0] = __builtin_amdgcn_mfma_f32_16x16x32_bf16(aF0, wF0, acc[0][0], 0, 0, 0); \
                acc[0][1] = __builtin_amdgcn_mfma_f32_16x16x32_bf16(aF0, wF1, acc[0][1], 0, 0, 0); \
                acc[0][2] = __builtin_amdgcn_mfma_f32_16x16x32_bf16(aF0, wF2, acc[0][2], 0, 0, 0); \
                acc[0][3] = __builtin_amdgcn_mfma_f32_16x16x32_bf16(aF0, wF3, acc[0][3], 0, 0, 0); \
            }                                                                        \
            if (rem > 16) {                                                          \
                acc[1][0] = __builtin_amdgcn_mfma_f32_16x16x32_bf16(aF1, wF0, acc[1][0], 0, 0, 0); \
                acc[1][1] = __builtin_amdgcn_mfma_f32_16x16x32_bf16(aF1, wF1, acc[1][1], 0, 0, 0); \
                acc[1][2] = __builtin_amdgcn_mfma_f32_16x16x32_bf16(aF1, wF2, acc[1][2], 0, 0, 0); \
                acc[1][3] = __builtin_amdgcn_mfma_f32_16x16x32_bf16(aF1, wF3, acc[1][3], 0, 0, 0); \
            }                                                                        \
            if (rem > 32) {                                                          \
                acc[2][0] = __builtin_amdgcn_mfma_f32_16x16x32_bf16(aF2, wF0, acc[2][0], 0, 0, 0); \
                acc[2][1] = __builtin_amdgcn_mfma_f32_16x16x32_bf16(aF2, wF1, acc[2][1], 0, 0, 0); \
                acc[2][2] = __builtin_amdgcn_mfma_f32_16x16x32_bf16(aF2, wF2, acc[2][2], 0, 0, 0); \
                acc[2][3] = __builtin_amdgcn_mfma_f32_16x16x32_bf16(aF2, wF3, acc[2][3], 0, 0, 0); \
            }                                                                        \
        }

        for (int s = 0; s < NS; s += 2) {
            // even step s: read buf0, write buf1
            if (s + 2 < NS) LOAD_WE(s + 2);
            GU_MFMA(smem)
            WRITE_WO(s + 1);
            WRITE_A(s + 1);
            if (s + 2 < NS) LOAD_A(s + 2);
            asm volatile("s_waitcnt lgkmcnt(0)" ::: "memory");
            __builtin_amdgcn_s_barrier();
            // odd step s+1: read buf1, write buf0
            if (s + 3 < NS) LOAD_WO(s + 3);
            GU_MFMA(smem + 12800)
            if (s + 2 < NS) { WRITE_WE(s + 2); WRITE_A(s + 2); }
            if (s + 3 < NS) LOAD_A(s + 3);
            asm volatile("s_waitcnt lgkmcnt(0)" ::: "memory");
            __builtin_amdgcn_s_barrier();
        }
        #undef GU_MFMA

        // ---- epilogue: up waves export acc via LDS (stride 65),
        //      gate waves combine h = silu(g)*u -> bf16 hb
        float* xbf = smemf;
        if (isUp) {
            #pragma unroll
            for (int ms = 0; ms < 3; ++ms)
                #pragma unroll
                for (int i = 0; i < 4; ++i) {
                    int lrow = wg * 48 + ms * 16 + fq * 4 + i;
                    #pragma unroll
                    for (int ns = 0; ns < 4; ++ns)
                        xbf[lrow * 65 + ns * 16 + fr] = acc[ms][ns][i];
                }
        }
        __syncthreads();
        if (!isUp) {
            #pragma unroll
            for (int ms = 0; ms < 3; ++ms)
                #pragma unroll
                for (int i = 0; i < 4; ++i) {
                    int lrow = wg * 48 + ms * 16 + fq * 4 + i;
                    int grow = m0 + lrow;
                    if (grow < nrows) {
                        unsigned short* drow = hb + (size_t)(r0 + grow) * MLP + n0;
                        #pragma unroll
                        for (int ns = 0; ns < 4; ++ns) {
                            float g = acc[ms][ns][i];
                            float u = xbf[lrow * 65 + ns * 16 + fr];
                            float h = g * u / (1.f + __expf(-g));
                            drow[ns * 16 + fr] = f2bf(h);
                        }
                    }
                }
        }
        __syncthreads();
    }
}

// ---------------------------------------------------------------------------
// down GEMM — ported to the PROVEN gateup structure: 512 thr = 8 waves,
// block tile M=192 x N=128, waves = 4 row-groups (48 rows) x 2 col-groups
// (64 cols).  Same LDS budget (51200 B), same E/O W register double-buffer,
// same raw-barrier pipeline -> 3 blocks/CU, 24 waves/CU (vs old 8 waves/CU).
// A (hb) is bf16, sorted, contiguous: no gather, no convert.
// Plain coalesced stores to pout[pair]; combine applies routing weights.
// ---------------------------------------------------------------------------
__global__ __launch_bounds__(512) void down2_kernel(
    const unsigned short* __restrict__ hb, const float* __restrict__ dw,
    const int* __restrict__ offsets, const int* __restrict__ rows,
    float* __restrict__ pout)
{
    // bijective XCD swizzle (1024 = 8 * 128): each XCD gets 8 whole experts
    const int bid = blockIdx.x;
    const int sw  = (bid & 7) * 128 + (bid >> 3);
    const int e   = sw >> 4;            // 16 blocks per expert
    const int n0  = (sw & 15) * 128;

    const int r0 = offsets[e];
    const int nrows = offsets[e + 1] - r0;
    if (nrows <= 0) return;

    // 2 buffers x (A 192*40 + W 128*40) shorts = 51200 B
    __shared__ __align__(16) unsigned short smem[2 * 12800];

    const int thr  = threadIdx.x;
    const int wave = thr >> 6;
    const int lane = thr & 63;
    const int wg   = wave & 3;          // row-group 0..3 (48 rows each)
    const int wc   = wave >> 2;         // col-group 0..1 (64 cols each)
    const int fr   = lane & 15;
    const int fq   = lane >> 4;

    // A staging: 768 slots of 16B (192 rows x 4 chunks); thread handles slot
    // thr (rows 0-127) and, for thr<256, slot thr+512 (rows 128-191).
    const int ar0 = thr >> 2;           // row 0..127
    const int ac  = (thr & 3) * 8;      // k-col in shorts (0,8,16,24)
    const int ar1 = 128 + (thr >> 2);   // rows 128..191 (thr<256 only)
    const bool hasS1 = thr < 256;

    // W staging: thread covers k rows 2*wk2,2*wk2+1 x 4 n cols (128 n total)
    const int wk2 = thr & 15;           // k = 2*wk2
    const int wnq = thr >> 4;           // n = wnq*4  (0..124)
    const float* wsrc = dw + (size_t)e * MLP * HID + (size_t)(2 * wk2) * HID + n0 + wnq * 4;

    const int NS = MLP / 32;            // 24 K-steps (even)

    for (int m0 = 0; m0 < nrows; m0 += 192) {
        const bool av0 = (m0 + ar0) < nrows;
        const bool av1 = hasS1 && (m0 + ar1) < nrows;
        const unsigned short* hp0 = hb + (size_t)(r0 + m0 + ar0) * MLP + ac;
        const unsigned short* hp1 = hb + (size_t)(r0 + m0 + ar1) * MLP + ac;

        u32x4 ua0, ua1;
        f32x4 w0e, w1e, w0o, w1o;
        const u32x4 uz = (u32x4){0u, 0u, 0u, 0u};
        const f32x4 fz = (f32x4){0.f, 0.f, 0.f, 0.f};

        auto LOAD_A = [&](int s) {
            ua0 = av0 ? *(const u32x4*)(hp0 + s * 32) : uz;
            ua1 = av1 ? *(const u32x4*)(hp1 + s * 32) : uz;
        };
        auto WRITE_A = [&](int s) {
            unsigned short* b = smem + (s & 1) * 12800;
            *(u32x4*)(b + ar0 * LDK + ac) = ua0;
            if (hasS1) *(u32x4*)(b + ar1 * LDK + ac) = ua1;
        };
        auto LOAD_WE = [&](int s) {
            const float* wp = wsrc + (size_t)s * 32 * HID;
            w0e = *(const f32x4*)wp;  w1e = *(const f32x4*)(wp + HID);
        };
        auto LOAD_WO = [&](int s) {
            const float* wp = wsrc + (size_t)s * 32 * HID;
            w0o = *(const f32x4*)wp;  w1o = *(const f32x4*)(wp + HID);
        };
        auto WRITE_WE = [&](int s) {
            unsigned short* wb = smem + (s & 1) * 12800 + 7680;
            #pragma unroll
            for (int i = 0; i < 4; ++i)
                *(unsigned int*)(wb + (wnq * 4 + i) * LDK + 2 * wk2) = pk2bf(w0e[i], w1e[i]);
        };
        auto WRITE_WO = [&](int s) {
            unsigned short* wb = smem + (s & 1) * 12800 + 7680;
            #pragma unroll
            for (int i = 0; i < 4; ++i)
                *(unsigned int*)(wb + (wnq * 4 + i) * LDK + 2 * wk2) = pk2bf(w0o[i], w1o[i]);
        };

        f32x4 acc[3][4];
        #pragma unroll
        for (int ms = 0; ms < 3; ++ms)
            #pragma unroll
            for (int ns = 0; ns < 4; ++ns) acc[ms][ns] = fz;

        const int rem = nrows - m0 - wg * 48;

        // prologue
        LOAD_WE(0);
        LOAD_WO(1);
        LOAD_A(0);
        WRITE_WE(0);
        WRITE_A(0);
        LOAD_A(1);
        asm volatile("s_waitcnt lgkmcnt(0)" ::: "memory");
        __builtin_amdgcn_s_barrier();

        #define DN_MFMA(BB)                                                          \
        {                                                                            \
            const unsigned short* wbb = (BB) + 7680;                                 \
            bf16x8 aF0, aF1, aF2, wF0, wF1, wF2, wF3;                                \
            wF0 = *(const bf16x8*)(wbb + (wc * 64 + 0 * 16 + fr) * LDK + fq * 8);    \
            wF1 = *(const bf16x8*)(wbb + (wc * 64 + 1 * 16 + fr) * LDK + fq * 8);    \
            wF2 = *(const bf16x8*)(wbb + (wc * 64 + 2 * 16 + fr) * LDK + fq * 8);    \
            wF3 = *(const bf16x8*)(wbb + (wc * 64 + 3 * 16 + fr) * LDK + fq * 8);    \
            aF0 = *(const bf16x8*)((BB) + (wg * 48 + fr) * LDK + fq * 8);            \
            aF1 = *(const bf16x8*)((BB) + (wg * 48 + 16 + fr) * LDK + fq * 8);       \
            aF2 = *(const bf16x8*)((BB) + (wg * 48 + 32 + fr) * LDK + fq * 8);       \
            if (rem > 0) {                                                           \
                acc[0][0] = __builtin_amdgcn_mfma_f32_16x16x32_bf16(aF0, wF0, acc[0][0], 0, 0, 0); \
                acc[0][1] = __builtin_amdgcn_mfma_f32_16x16x32_bf16(aF0, wF1, acc[0][1], 0, 0, 0); \
                acc[0][2] = __builtin_amdgcn_mfma_f32_16x16x32_bf16(aF0, wF2, acc[0][2], 0, 0, 0); \
                acc[0][3] = __builtin_amdgcn_mfma_f32_16x16x32_bf16(aF0, wF3, acc[0][3], 0, 0, 0); \
            }                                                                        \
            if (rem > 16) {                                                          \
                acc[1][0] = __builtin_amdgcn_mfma_f32_16x16x32_bf16(aF1, wF0, acc[1][0], 0, 0, 0); \
                acc[1][1] = __builtin_amdgcn_mfma_f32_16x16x32_bf16(aF1, wF1, acc[1][1], 0, 0, 0); \
                acc[1][2] = __builtin_amdgcn_mfma_f32_16x16x32_bf16(aF1, wF2, acc[1][2], 0, 0, 0); \
                acc[1][3] = __builtin_amdgcn_mfma_f32_16x16x32_bf16(aF1, wF3, acc[1][3], 0, 0, 0); \
            }                                                                        \
            if (rem > 32) {                                                          \
                acc[2][0] = __builtin_amdgcn_mfma_f32_16x16x32_bf16(aF2, wF0, acc[2][0], 0, 0, 0); \
                acc[2][1] = __builtin_amdgcn_mfma_f32_16x16x32_bf16(aF2, wF1, acc[2][1], 0, 0, 0); \
                acc[2][2] = __builtin_amdgcn_mfma_f32_16x16x32_bf16(aF2, wF2, acc[2][2], 0, 0, 0); \
                acc[2][3] = __builtin_amdgcn_mfma_f32_16x16x32_bf16(aF2, wF3, acc[2][3], 0, 0, 0); \
            }                                                                        \
        }

        for (int s = 0; s < NS; s += 2) {
            // even step s: read buf0, write buf1
            if (s + 2 < NS) LOAD_WE(s + 2);
            DN_MFMA(smem)
            WRITE_WO(s + 1);
            WRITE_A(s + 1);
            if (s + 2 < NS) LOAD_A(s + 2);
            asm volatile("s_waitcnt lgkmcnt(0)" ::: "memory");
            __builtin_amdgcn_s_barrier();
            // odd step s+1: read buf1, write buf0
            if (s + 3 < NS) LOAD_WO(s + 3);
            DN_MFMA(smem + 12800)
            if (s + 2 < NS) { WRITE_WE(s + 2); WRITE_A(s + 2); }
            if (s + 3 < NS) LOAD_A(s + 3);
            asm volatile("s_waitcnt lgkmcnt(0)" ::: "memory");
            __builtin_amdgcn_s_barrier();
        }
        #undef DN_MFMA

        // epilogue: plain coalesced stores to per-pair buffer (no atomics)
        #pragma unroll
        for (int ms = 0; ms < 3; ++ms) {
            #pragma unroll
            for (int i = 0; i < 4; ++i) {
                int grow = m0 + wg * 48 + ms * 16 + fq * 4 + i;
                if (grow < nrows) {
                    int p = rows[r0 + grow];
                    float* orow = pout + (size_t)p * HID + n0 + wc * 64;
                    #pragma unroll
                    for (int ns = 0; ns < 4; ++ns)
                        orow[ns * 16 + fr] = acc[ms][ns][i];
                }
            }
        }
        __syncthreads();
    }
}

// ---------------------------------------------------------------------------
// FALLBACK down (atomic) — only used when workspace can't hold pout.
// ---------------------------------------------------------------------------
__global__ __launch_bounds__(256, 2) void down_atomic_kernel(
    const unsigned short* __restrict__ hb, const float* __restrict__ dw,
    const int* __restrict__ offsets, const int* __restrict__ rows,
    const float* __restrict__ wts, float* __restrict__ out)
{
    const int bid = blockIdx.x;
    const int sw  = (bid & 7) * 128 + (bid >> 3);
    const int e   = sw >> 4;
    const int n0  = (sw & 15) * 128;

    const int r0 = offsets[e];
    const int nrows = offsets[e + 1] - r0;
    if (nrows <= 0) return;

    __shared__ __align__(16) float smemf[12800];
    unsigned short* smem = (unsigned short*)smemf;

    const int thr  = threadIdx.x;
    const int wave = thr >> 6;
    const int lane = thr & 63;
    const int wg   = wave & 1;
    const int wn   = wave >> 1;
    const int fr   = lane & 15;
    const int fq   = lane >> 4;

    const int ar = thr >> 2;
    const int ac = (thr & 3) * 8;

    const int wk2 = thr & 15;
    const int nst = (thr >> 4) * 8;
    const float* wsrc = dw + (size_t)e * MLP * HID + (size_t)(2 * wk2) * HID + n0 + nst;

    const int NS = MLP / 32;

    for (int m0 = 0; m0 < nrows; m0 += 192) {
        const bool av0 = (m0 + ar)       < nrows;
        const bool av1 = (m0 + ar + 64)  < nrows;
        const bool av2 = (m0 + ar + 128) < nrows;
        const unsigned short* hp0 = hb + (size_t)(r0 + m0 + ar) * MLP + ac;
        const unsigned short* hp1 = hp0 + (size_t)64  * MLP;
        const unsigned short* hp2 = hp0 + (size_t)128 * MLP;

        u32x4 ua0, ua1, ua2;
        f32x4 wAe, wBe, wCe, wDe, wAo, wBo, wCo, wDo;
        const u32x4 uz = (u32x4){0u, 0u, 0u, 0u};
        const f32x4 fz = (f32x4){0.f, 0.f, 0.f, 0.f};

        auto LOAD_A = [&](int s) {
            ua0 = av0 ? *(const u32x4*)(hp0 + s * 32) : uz;
            ua1 = av1 ? *(const u32x4*)(hp1 + s * 32) : uz;
            ua2 = av2 ? *(const u32x4*)(hp2 + s * 32) : uz;
        };
        auto WRITE_A = [&](int s) {
            unsigned short* b = smem + (s & 1) * 12800;
            *(u32x4*)(b + ar * LDK + ac) = ua0;
            *(u32x4*)(b + (ar + 64) * LDK + ac) = ua1;
            *(u32x4*)(b + (ar + 128) * LDK + ac) = ua2;
        };
        auto LOAD_WE = [&](int s) {
            const float* wp = wsrc + (size_t)s * 32 * HID;
            wAe = *(const f32x4*)wp;        wBe = *(const f32x4*)(wp + 4);
            wCe = *(const f32x4*)(wp + HID); wDe = *(const f32x4*)(wp + HID + 4);
        };
        auto LOAD_WO = [&](int s) {
            const float* wp = wsrc + (size_t)s * 32 * HID;
            wAo = *(const f32x4*)wp;        wBo = *(const f32x4*)(wp + 4);
            wCo = *(const f32x4*)(wp + HID); wDo = *(const f32x4*)(wp + HID + 4);
        };
        auto WRITE_WE = [&](int s) {
            unsigned short* wb = smem + (s & 1) * 12800 + 7680;
            #pragma unroll
            for (int j = 0; j < 4; ++j) {
                *(unsigned int*)(wb + (nst + j) * LDK + 2 * wk2)     = pk2bf(wAe[j], wCe[j]);
                *(unsigned int*)(wb + (nst + 4 + j) * LDK + 2 * wk2) = pk2bf(wBe[j], wDe[j]);
            }
        };
        auto WRITE_WO = [&](int s) {
            unsigned short* wb = smem + (s & 1) * 12800 + 7680;
            #pragma unroll
            for (int j = 0; j < 4; ++j) {
                *(unsigned int*)(wb + (nst + j) * LDK + 2 * wk2)     = pk2bf(wAo[j], wCo[j]);
                *(unsigned int*)(wb + (nst + 4 + j) * LDK + 2 * wk2) = pk2bf(wBo[j], wDo[j]);
            }
        };

        f32x4 acc[6][4];
        #pragma unroll
        for (int ms = 0; ms < 6; ++ms)
            #pragma unroll
            for (int ns = 0; ns < 4; ++ns) acc[ms][ns] = fz;

        const int rem = nrows - m0 - wg * 96;

        auto STEP = [&](const unsigned short* bb) {
            const unsigned short* wbb = bb + 7680;
            bf16x8 wF0 = *(const bf16x8*)(wbb + (wn * 64 + 0 * 16 + fr) * LDK + fq * 8);
            bf16x8 wF1 = *(const bf16x8*)(wbb + (wn * 64 + 1 * 16 + fr) * LDK + fq * 8);
            bf16x8 wF2 = *(const bf16x8*)(wbb + (wn * 64 + 2 * 16 + fr) * LDK + fq * 8);
            bf16x8 wF3 = *(const bf16x8*)(wbb + (wn * 64 + 3 * 16 + fr) * LDK + fq * 8);
            bf16x8 aF[6];
            #pragma unroll
            for (int ms = 0; ms < 6; ++ms)
                aF[ms] = *(const bf16x8*)(bb + (wg * 96 + ms * 16 + fr) * LDK + fq * 8);
            #pragma unroll
            for (int ms = 0; ms < 6; ++ms) {
                if (rem > ms * 16) {
                    acc[ms][0] = __builtin_amdgcn_mfma_f32_16x16x32_bf16(aF[ms], wF0, acc[ms][0], 0, 0, 0);
                    acc[ms][1] = __builtin_amdgcn_mfma_f32_16x16x32_bf16(aF[ms], wF1, acc[ms][1], 0, 0, 0);
                    acc[ms][2] = __builtin_amdgcn_mfma_f32_16x16x32_bf16(aF[ms], wF2, acc[ms][2], 0, 0, 0);
                    acc[ms][3] = __builtin_amdgcn_mfma_f32_16x16x32_bf16(aF[ms], wF3, acc[ms][3], 0, 0, 0);
                }
            }
        };

        LOAD_WE(0);
        LOAD_WO(1);
        LOAD_A(0);
        WRITE_WE(0);
        WRITE_A(0);
        LOAD_A(1);
        asm volatile("s_waitcnt lgkmcnt(0)" ::: "memory");
        __builtin_amdgcn_s_barrier();

        for (int s = 0; s < NS; s += 2) {
            if (s + 2 < NS) LOAD_WE(s + 2);
            STEP(smem);
            WRITE_WO(s + 1);
            WRITE_A(s + 1);
            if (s + 2 < NS) LOAD_A(s + 2);
            asm volatile("s_waitcnt lgkmcnt(0)" ::: "memory");
            __builtin_amdgcn_s_barrier();
            if (s + 3 < NS) LOAD_WO(s + 3);
            STEP(smem + 12800);
            if (s + 2 < NS) { WRITE_WE(s + 2); WRITE_A(s + 2); }
            if (s + 3 < NS) LOAD_A(s + 3);
            asm volatile("s_waitcnt lgkmcnt(0)" ::: "memory");
            __builtin_amdgcn_s_barrier();
        }

        #pragma unroll
        for (int ms = 0; ms < 6; ++ms) {
            #pragma unroll
            for (int i = 0; i < 4; ++i) {
                int lrow = wg * 96 + ms * 16 + fq * 4 + i;
                int grow = m0 + lrow;
                if (grow < nrows) {
                    int p = rows[r0 + grow];
                    float w = wts[p];
                    float* orow = out + (size_t)(p >> 3) * HID + n0 + wn * 64;
                    #pragma unroll
                    for (int ns = 0; ns < 4; ++ns)
                        atomicAdd(orow + ns * 16 + fr, acc[ms][ns][i] * w);
                }
            }
        }
        __syncthreads();
    }
}

// ---------------------------------------------------------------------------
// combine: out[t] = sum_j wts[t*8+j] * pout[t*8+j]  (fully coalesced)
// ---------------------------------------------------------------------------
__global__ __launch_bounds__(256) void combine_kernel(
    const float* __restrict__ pout, const float* __restrict__ wts,
    float* __restrict__ out)
{
    const int idx = blockIdx.x * 256 + threadIdx.x;   // one f32x4 per thread
    const int t   = idx >> 9;                         // HID/4 = 512 chunks/token
    const int c4  = (idx & 511) * 4;

    const float* w8 = wts + t * TOPK;
    const float* pr = pout + (size_t)t * TOPK * HID + c4;
    f32x4 s = (f32x4){0.f, 0.f, 0.f, 0.f};
    #pragma unroll
    for (int j = 0; j < TOPK; ++j) {
        f32x4 v = *(const f32x4*)(pr + (size_t)j * HID);
        float w = w8[j];
        s[0] += w * v[0]; s[1] += w * v[1]; s[2] += w * v[2]; s[3] += w * v[3];
    }
    *(f32x4*)(out + (size_t)t * HID + c4) = s;
}

// ---------------------------------------------------------------------------
extern "C" void kernel_launch(void* const* d_in, const int* in_sizes, int n_in,
                              void* d_out, int out_size, void* d_ws, size_t ws_size,
                              hipStream_t stream)
{
    const float* hs = (const float*)d_in[0];   // [1024, 2048]
    const float* rw = (const float*)d_in[1];   // [2048, 64]
    const float* gw = (const float*)d_in[2];   // [64, 2048, 768]
    const float* uw = (const float*)d_in[3];   // [64, 2048, 768]
    const float* dw = (const float*)d_in[4];   // [64, 768, 2048]
    float* out = (float*)d_out;                // [1024, 2048]

    char* ws = (char*)d_ws;
    int*   sel     = (int*)(ws);                         // 8192 ints
    float* wts     = (float*)(ws + 32768);               // 8192 floats
    int*   offsets = (int*)(ws + 65792);                 // 65
    int*   rows    = (int*)(ws + 66560);                 // 8192
    unsigned short* xb = (unsigned short*)(ws + 99328);            // 4 MB bf16
    unsigned short* hb = (unsigned short*)(ws + 99328 + 4194304);  // 12.6 MB bf16
    float* pout = (float*)(ws + 99328 + 4194304 + 12582912);       // 67 MB f32
    const size_t need = 99328ull + 4194304 + 12582912 + (size_t)NPAIR * HID * 4;

    router_topk_kernel<<<T_TOKENS / 4, 256, 0, stream>>>(hs, rw, sel, wts, xb);
    route_kernel<<<1, 1024, 0, stream>>>(sel, offsets, rows);
    gateup_kernel<<<768, 512, 0, stream>>>(xb, gw, uw, offsets, rows, hb);

    if (ws_size >= need) {
        // atomic-free path: down -> per-pair buffer, then weighted combine
        down2_kernel<<<1024, 512, 0, stream>>>(hb, dw, offsets, rows, pout);
        combine_kernel<<<T_TOKENS * HID / 4 / 256, 256, 0, stream>>>(pout, wts, out);
    } else {
        hipMemsetAsync(out, 0, (size_t)T_TOKENS * HID * sizeof(float), stream);
        down_atomic_kernel<<<1024, 256, 0, stream>>>(hb, dw, offsets, rows, wts, out);
    }
}

// Round 10
// 1161.168 us; speedup vs baseline: 1.0157x; 1.0157x over previous
//
#include <hip/hip_runtime.h>
#include <hip/hip_bf16.h>

// Sizes (fixed by the reference)
#define T_TOKENS 1024
#define HID      2048
#define NEXP     64
#define TOPK     8
#define MLP      768
#define NPAIR    (T_TOKENS * TOPK)   // 8192

typedef __bf16 bf16x8 __attribute__((ext_vector_type(8)));
typedef float  f32x4  __attribute__((ext_vector_type(4)));
typedef unsigned int u32x2 __attribute__((ext_vector_type(2)));
typedef unsigned int u32x4 __attribute__((ext_vector_type(4)));

#define LDK 40   // LDS row stride in shorts (16B-aligned b128 frag reads, 2-way-max bank aliasing)

static __device__ __forceinline__ unsigned short f2bf(float f) {
    __hip_bfloat16 h = __float2bfloat16(f);
    unsigned short u;
    __builtin_memcpy(&u, &h, sizeof(u));
    return u;
}
static __device__ __forceinline__ unsigned int pk2bf(float a, float b) {
    return (unsigned int)f2bf(a) | ((unsigned int)f2bf(b) << 16);
}

// ---------------------------------------------------------------------------
// Router: logits = hs @ router_w, top-8, softmax over the 8.  Each wave also
// converts its token row fp32->bf16 into xb (cvt kernel folded in).
// ---------------------------------------------------------------------------
__global__ __launch_bounds__(256) void router_topk_kernel(
    const float* __restrict__ hs, const float* __restrict__ rw,
    int* __restrict__ sel, float* __restrict__ wts, unsigned short* __restrict__ xb)
{
    const int lane = threadIdx.x & 63;
    const int tg   = threadIdx.x >> 6;
    const int t    = blockIdx.x * 4 + tg;

    // fold-in: convert this token's row to bf16
    {
        const float* xr = hs + (size_t)t * HID;
        unsigned short* xw = xb + (size_t)t * HID;
        #pragma unroll
        for (int c = 0; c < 4; ++c) {
            int i = (lane + c * 64) * 8;
            f32x4 a = *(const f32x4*)(xr + i);
            f32x4 b = *(const f32x4*)(xr + i + 4);
            u32x4 v;
            v[0] = pk2bf(a[0], a[1]); v[1] = pk2bf(a[2], a[3]);
            v[2] = pk2bf(b[0], b[1]); v[3] = pk2bf(b[2], b[3]);
            *(u32x4*)(xw + i) = v;
        }
    }

    const float4* x4 = (const float4*)(hs + (size_t)t * HID);
    float acc = 0.f;
    for (int h4 = 0; h4 < HID / 4; ++h4) {
        float4 xv = x4[h4];
        int hb = h4 * 4 * NEXP + lane;
        acc += xv.x * rw[hb] + xv.y * rw[hb + NEXP]
             + xv.z * rw[hb + 2 * NEXP] + xv.w * rw[hb + 3 * NEXP];
    }

    float v = acc;
    float tv[TOPK]; int ti[TOPK];
    for (int i = 0; i < TOPK; ++i) {
        float m = v; int mi = lane;
        for (int off = 32; off > 0; off >>= 1) {
            float om  = __shfl_xor(m, off, 64);
            int   omi = __shfl_xor(mi, off, 64);
            if (om > m || (om == m && omi < mi)) { m = om; mi = omi; }
        }
        tv[i] = m; ti[i] = mi;
        if (lane == mi) v = -__builtin_inff();
    }
    if (lane == 0) {
        float mx = tv[0], s = 0.f, e[TOPK];
        for (int i = 0; i < TOPK; ++i) { e[i] = __expf(tv[i] - mx); s += e[i]; }
        float inv = 1.f / s;
        for (int i = 0; i < TOPK; ++i) {
            wts[t * TOPK + i] = e[i] * inv;
            sel[t * TOPK + i] = ti[i];
        }
    }
}

// ---------------------------------------------------------------------------
// Routing bookkeeping: count + scan + scatter in ONE kernel (1 block, LDS).
// ---------------------------------------------------------------------------
__global__ __launch_bounds__(1024) void route_kernel(
    const int* __restrict__ sel, int* __restrict__ offsets, int* __restrict__ rows)
{
    __shared__ int cnt[NEXP];
    __shared__ int cur[NEXP];
    const int t = threadIdx.x;
    if (t < NEXP) cnt[t] = 0;
    __syncthreads();
    int e[8];
    const int p0 = t * 8;
    #pragma unroll
    for (int j = 0; j < 8; ++j) {
        e[j] = sel[p0 + j];
        atomicAdd(&cnt[e[j]], 1);
    }
    __syncthreads();
    if (t == 0) {
        int s = 0;
        for (int i = 0; i < NEXP; ++i) { cur[i] = s; offsets[i] = s; s += cnt[i]; }
        offsets[NEXP] = s;
    }
    __syncthreads();
    #pragma unroll
    for (int j = 0; j < 8; ++j) {
        int pos = atomicAdd(&cur[e[j]], 1);
        rows[pos] = p0 + j;   // pair id; token = p>>3
    }
}

// ---------------------------------------------------------------------------
// gate/up GEMM + SiLU fused.  EXACT best-known kernel (272-276 us).
// Block = 512 threads = 8 waves.  Waves 0-3: gate, waves 4-7: up, each
// 48 rows x 64 cols.  A bf16 from xb via LDS; W E/O register double-buffer;
// raw s_barrier + lgkmcnt(0) only (vmcnt stays counted in the main loop).
// FROZEN — 5 redesigns all measured worse or neutral.
// ---------------------------------------------------------------------------
__global__ __launch_bounds__(512) void gateup_kernel(
    const unsigned short* __restrict__ xb, const float* __restrict__ gw,
    const float* __restrict__ uw, const int* __restrict__ offsets,
    const int* __restrict__ rows, unsigned short* __restrict__ hb)
{
    // bijective XCD swizzle (768 = 8 * 96): each XCD gets 8 whole experts
    const int bid = blockIdx.x;
    const int sw  = (bid & 7) * 96 + (bid >> 3);
    const int e   = sw / 12;
    const int n0  = (sw % 12) * 64;

    const int r0 = offsets[e];
    const int nrows = offsets[e + 1] - r0;
    if (nrows <= 0) return;

    // 2 buffers x (A 192*40 + G 64*40 + U 64*40) shorts = 51200 B
    __shared__ __align__(16) float smemf[12800];
    unsigned short* smem = (unsigned short*)smemf;

    const int thr  = threadIdx.x;
    const int wave = thr >> 6;
    const int lane = thr & 63;
    const int wg   = wave & 3;          // row-group 0..3 (48 rows each)
    const int isUp = wave >> 2;         // waves 4-7 do up
    const int fr   = lane & 15;
    const int fq   = lane >> 4;

    // A staging: u32x2 (4 bf16) per slot; rows ar, ar+64, ar+128
    const int ar = thr >> 3;            // row 0..63
    const int ac = (thr & 7) * 4;       // k-col in shorts (0,4,..,28)

    // W staging: thr<256 -> gate, thr>=256 -> up; pair-slot = (k2, nq)
    const int wk2 = thr & 15;           // k = 2*wk2
    const int wnq = (thr & 255) >> 4;   // n = wnq*4
    const float* wsrc = (thr >= 256 ? uw : gw)
        + (size_t)e * HID * MLP + (size_t)(2 * wk2) * MLP + n0 + wnq * 4;
    const int mofs = (thr >= 256) ? 10240 : 7680;  // U / G region

    const int NS = HID / 32;            // 64 K-steps (even)

    for (int m0 = 0; m0 < nrows; m0 += 192) {
        // ---- hoist gather pointers (rows[] read once per m-pass)
        const unsigned short *ap0, *ap1, *ap2;
        bool av0, av1, av2;
        {
            int gr0 = m0 + ar, gr1 = m0 + ar + 64, gr2 = m0 + ar + 128;
            av0 = gr0 < nrows; av1 = gr1 < nrows; av2 = gr2 < nrows;
            int p0 = av0 ? rows[r0 + gr0] : 0;
            int p1 = av1 ? rows[r0 + gr1] : 0;
            int p2 = av2 ? rows[r0 + gr2] : 0;
            ap0 = xb + (size_t)(p0 >> 3) * HID + ac;
            ap1 = xb + (size_t)(p1 >> 3) * HID + ac;
            ap2 = xb + (size_t)(p2 >> 3) * HID + ac;
        }

        u32x2 va0, va1, va2;
        f32x4 w0e, w1e, w0o, w1o;
        const u32x2 z2 = (u32x2){0u, 0u};
        const f32x4 fz = (f32x4){0.f, 0.f, 0.f, 0.f};

        auto LOAD_A = [&](int s) {
            va0 = av0 ? *(const u32x2*)(ap0 + s * 32) : z2;
            va1 = av1 ? *(const u32x2*)(ap1 + s * 32) : z2;
            va2 = av2 ? *(const u32x2*)(ap2 + s * 32) : z2;
        };
        auto WRITE_A = [&](int s) {
            unsigned short* b = smem + (s & 1) * 12800;
            *(u32x2*)(b + ar * LDK + ac) = va0;
            *(u32x2*)(b + (ar + 64) * LDK + ac) = va1;
            *(u32x2*)(b + (ar + 128) * LDK + ac) = va2;
        };
        auto LOAD_WE = [&](int s) {
            const float* wp = wsrc + (size_t)s * 32 * MLP;
            w0e = *(const f32x4*)wp;  w1e = *(const f32x4*)(wp + MLP);
        };
        auto LOAD_WO = [&](int s) {
            const float* wp = wsrc + (size_t)s * 32 * MLP;
            w0o = *(const f32x4*)wp;  w1o = *(const f32x4*)(wp + MLP);
        };
        auto WRITE_WE = [&](int s) {
            unsigned short* wb = smem + (s & 1) * 12800 + mofs;
            #pragma unroll
            for (int i = 0; i < 4; ++i)
                *(unsigned int*)(wb + (wnq * 4 + i) * LDK + 2 * wk2) = pk2bf(w0e[i], w1e[i]);
        };
        auto WRITE_WO = [&](int s) {
            unsigned short* wb = smem + (s & 1) * 12800 + mofs;
            #pragma unroll
            for (int i = 0; i < 4; ++i)
                *(unsigned int*)(wb + (wnq * 4 + i) * LDK + 2 * wk2) = pk2bf(w0o[i], w1o[i]);
        };

        f32x4 acc[3][4];
        #pragma unroll
        for (int ms = 0; ms < 3; ++ms)
            #pragma unroll
            for (int ns = 0; ns < 4; ++ns) acc[ms][ns] = fz;

        const int rem = nrows - m0 - wg * 48;

        // prologue
        LOAD_WE(0);
        LOAD_WO(1);
        LOAD_A(0);
        WRITE_WE(0);
        WRITE_A(0);
        LOAD_A(1);
        asm volatile("s_waitcnt lgkmcnt(0)" ::: "memory");
        __builtin_amdgcn_s_barrier();

        #define GU_MFMA(BB)                                                          \
        {                                                                            \
            const unsigned short* wbb = (BB) + mofs;                                 \
            bf16x8 aF0, aF1, aF2, wF0, wF1, wF2, wF3;                                \
            wF0 = *(const bf16x8*)(wbb + (0 * 16 + fr) * LDK + fq * 8);              \
            wF1 = *(const bf16x8*)(wbb + (1 * 16 + fr) * LDK + fq * 8);              \
            wF2 = *(const bf16x8*)(wbb + (2 * 16 + fr) * LDK + fq * 8);              \
            wF3 = *(const bf16x8*)(wbb + (3 * 16 + fr) * LDK + fq * 8);              \
            aF0 = *(const bf16x8*)((BB) + (wg * 48 + fr) * LDK + fq * 8);            \
            aF1 = *(const bf16x8*)((BB) + (wg * 48 + 16 + fr) * LDK + fq * 8);       \
            aF2 = *(const bf16x8*)((BB) + (wg * 48 + 32 + fr) * LDK + fq * 8);       \
            if (rem > 0) {                                                           \
                acc[0][0] = __builtin_amdgcn_mfma_f32_16x16x32_bf16(aF0, wF0, acc[0][0], 0, 0, 0); \
                acc[0][1] = __builtin_amdgcn_mfma_f32_16x16x32_bf16(aF0, wF1, acc[0][1], 0, 0, 0); \
                acc[0][2] = __builtin_amdgcn_mfma_f32_16x16x32_bf16(aF0, wF2, acc[0][2], 0, 0, 0); \
                acc[0][3] = __builtin_amdgcn_mfma_f32_16x16x32_bf16(aF0, wF3, acc[0][3], 0, 0, 0); \
            }                                                                        \
            if (rem > 16) {                                                          \
                acc[1][0] = __builtin_amdgcn_mfma_f32_16x16x32_bf16(aF1, wF0, acc[1][0], 0, 0, 0); \
                acc[1][1] = __builtin_amdgcn_mfma_f32_16x16x32_bf16(aF1, wF1, acc[1][1], 0, 0, 0); \
                acc[1][2] = __builtin_amdgcn_mfma_f32_16x16x32_bf16(aF1, wF2, acc[1][2], 0, 0, 0); \
                acc[1][3] = __builtin_amdgcn_mfma_f32_16x16x32_bf16(aF1, wF3, acc[1][3], 0, 0, 0); \
            }                                                                        \
            if (rem > 32) {                                                          \
                acc[2][0] = __builtin_amdgcn_mfma_f32_16x16x32_bf16(aF2, wF0, acc[2][0], 0, 0, 0); \
                acc[2][1] = __builtin_amdgcn_mfma_f32_16x16x32_bf16(aF2, wF1, acc[2][1], 0, 0, 0); \
                acc[2][2] = __builtin_amdgcn_mfma_f32_16x16x32_bf16(aF2, wF2, acc[2][2], 0, 0, 0); \
                acc[2][3] = __builtin_amdgcn_mfma_f32_16x16x32_bf16(aF2, wF3, acc[2][3], 0, 0, 0); \
            }                                                                        \
        }

        for (int s = 0; s < NS; s += 2) {
            // even step s: read buf0, write buf1
            if (s + 2 < NS) LOAD_WE(s + 2);
            GU_MFMA(smem)
            WRITE_WO(s + 1);
            WRITE_A(s + 1);
            if (s + 2 < NS) LOAD_A(s + 2);
            asm volatile("s_waitcnt lgkmcnt(0)" ::: "memory");
            __builtin_amdgcn_s_barrier();
            // odd step s+1: read buf1, write buf0
            if (s + 3 < NS) LOAD_WO(s + 3);
            GU_MFMA(smem + 12800)
            if (s + 2 < NS) { WRITE_WE(s + 2); WRITE_A(s + 2); }
            if (s + 3 < NS) LOAD_A(s + 3);
            asm volatile("s_waitcnt lgkmcnt(0)" ::: "memory");
            __builtin_amdgcn_s_barrier();
        }
        #undef GU_MFMA

        // ---- epilogue: up waves export acc via LDS (stride 65),
        //      gate waves combine h = silu(g)*u -> bf16 hb
        float* xbf = smemf;
        if (isUp) {
            #pragma unroll
            for (int ms = 0; ms < 3; ++ms)
                #pragma unroll
                for (int i = 0; i < 4; ++i) {
                    int lrow = wg * 48 + ms * 16 + fq * 4 + i;
                    #pragma unroll
                    for (int ns = 0; ns < 4; ++ns)
                        xbf[lrow * 65 + ns * 16 + fr] = acc[ms][ns][i];
                }
        }
        __syncthreads();
        if (!isUp) {
            #pragma unroll
            for (int ms = 0; ms < 3; ++ms)
                #pragma unroll
                for (int i = 0; i < 4; ++i) {
                    int lrow = wg * 48 + ms * 16 + fq * 4 + i;
                    int grow = m0 + lrow;
                    if (grow < nrows) {
                        unsigned short* drow = hb + (size_t)(r0 + grow) * MLP + n0;
                        #pragma unroll
                        for (int ns = 0; ns < 4; ++ns) {
                            float g = acc[ms][ns][i];
                            float u = xbf[lrow * 65 + ns * 16 + fr];
                            float h = g * u / (1.f + __expf(-g));
                            drow[ns * 16 + fr] = f2bf(h);
                        }
                    }
                }
        }
        __syncthreads();
    }
}

// ---------------------------------------------------------------------------
// down GEMM (best-measured R8 config): block tile M=192 x N=128, 256 thr =
// 4 waves of 96x64.  Epilogue: PLAIN coalesced f32 stores into pout[pair]
// (no atomics); routing-weight combine happens in combine_kernel.
// ---------------------------------------------------------------------------
template <int USE_ATOMIC>
__global__ __launch_bounds__(256, 2) void down_kernel_t(
    const unsigned short* __restrict__ hb, const float* __restrict__ dw,
    const int* __restrict__ offsets, const int* __restrict__ rows,
    const float* __restrict__ wts, float* __restrict__ outp)
{
    // bijective XCD swizzle (1024 = 8 * 128): each XCD gets 8 whole experts
    const int bid = blockIdx.x;
    const int sw  = (bid & 7) * 128 + (bid >> 3);
    const int e   = sw >> 4;            // 16 blocks per expert
    const int n0  = (sw & 15) * 128;

    const int r0 = offsets[e];
    const int nrows = offsets[e + 1] - r0;
    if (nrows <= 0) return;

    // 2 buffers x (A 192*40 + W 128*40) shorts = 51200 B
    __shared__ __align__(16) float smemf[12800];
    unsigned short* smem = (unsigned short*)smemf;

    const int thr  = threadIdx.x;
    const int wave = thr >> 6;
    const int lane = thr & 63;
    const int wg   = wave & 1;          // row-group (96 rows)
    const int wn   = wave >> 1;         // col-group (64 cols)
    const int fr   = lane & 15;
    const int fq   = lane >> 4;

    // A staging: 16B chunk per slot; rows ar, ar+64, ar+128
    const int ar = thr >> 2;            // row 0..63
    const int ac = (thr & 3) * 8;       // k-col in shorts (0,8,16,24)

    // W staging: 32k x 128n; each thread: 2 k-rows x 8 n
    const int wk2 = thr & 15;           // k = 2*wk2
    const int nst = (thr >> 4) * 8;     // n base (0,8,..,120)
    const float* wsrc = dw + (size_t)e * MLP * HID + (size_t)(2 * wk2) * HID + n0 + nst;

    const int NS = MLP / 32;            // 24 K-steps (even)

    for (int m0 = 0; m0 < nrows; m0 += 192) {
        const bool av0 = (m0 + ar)       < nrows;
        const bool av1 = (m0 + ar + 64)  < nrows;
        const bool av2 = (m0 + ar + 128) < nrows;
        const unsigned short* hp0 = hb + (size_t)(r0 + m0 + ar) * MLP + ac;
        const unsigned short* hp1 = hp0 + (size_t)64  * MLP;
        const unsigned short* hp2 = hp0 + (size_t)128 * MLP;

        u32x4 ua0, ua1, ua2;
        f32x4 wAe, wBe, wCe, wDe, wAo, wBo, wCo, wDo;
        const u32x4 uz = (u32x4){0u, 0u, 0u, 0u};
        const f32x4 fz = (f32x4){0.f, 0.f, 0.f, 0.f};

        auto LOAD_A = [&](int s) {
            ua0 = av0 ? *(const u32x4*)(hp0 + s * 32) : uz;
            ua1 = av1 ? *(const u32x4*)(hp1 + s * 32) : uz;
            ua2 = av2 ? *(const u32x4*)(hp2 + s * 32) : uz;
        };
        auto WRITE_A = [&](int s) {
            unsigned short* b = smem + (s & 1) * 12800;
            *(u32x4*)(b + ar * LDK + ac) = ua0;
            *(u32x4*)(b + (ar + 64) * LDK + ac) = ua1;
            *(u32x4*)(b + (ar + 128) * LDK + ac) = ua2;
        };
        auto LOAD_WE = [&](int s) {
            const float* wp = wsrc + (size_t)s * 32 * HID;
            wAe = *(const f32x4*)wp;        wBe = *(const f32x4*)(wp + 4);
            wCe = *(const f32x4*)(wp + HID); wDe = *(const f32x4*)(wp + HID + 4);
        };
        auto LOAD_WO = [&](int s) {
            const float* wp = wsrc + (size_t)s * 32 * HID;
            wAo = *(const f32x4*)wp;        wBo = *(const f32x4*)(wp + 4);
            wCo = *(const f32x4*)(wp + HID); wDo = *(const f32x4*)(wp + HID + 4);
        };
        auto WRITE_WE = [&](int s) {
            unsigned short* wb = smem + (s & 1) * 12800 + 7680;
            #pragma unroll
            for (int j = 0; j < 4; ++j) {
                *(unsigned int*)(wb + (nst + j) * LDK + 2 * wk2)     = pk2bf(wAe[j], wCe[j]);
                *(unsigned int*)(wb + (nst + 4 + j) * LDK + 2 * wk2) = pk2bf(wBe[j], wDe[j]);
            }
        };
        auto WRITE_WO = [&](int s) {
            unsigned short* wb = smem + (s & 1) * 12800 + 7680;
            #pragma unroll
            for (int j = 0; j < 4; ++j) {
                *(unsigned int*)(wb + (nst + j) * LDK + 2 * wk2)     = pk2bf(wAo[j], wCo[j]);
                *(unsigned int*)(wb + (nst + 4 + j) * LDK + 2 * wk2) = pk2bf(wBo[j], wDo[j]);
            }
        };

        f32x4 acc[6][4];
        #pragma unroll
        for (int ms = 0; ms < 6; ++ms)
            #pragma unroll
            for (int ns = 0; ns < 4; ++ns) acc[ms][ns] = fz;

        const int rem = nrows - m0 - wg * 96;

        auto STEP = [&](const unsigned short* bb) {
            const unsigned short* wbb = bb + 7680;
            bf16x8 wF0 = *(const bf16x8*)(wbb + (wn * 64 + 0 * 16 + fr) * LDK + fq * 8);
            bf16x8 wF1 = *(const bf16x8*)(wbb + (wn * 64 + 1 * 16 + fr) * LDK + fq * 8);
            bf16x8 wF2 = *(const bf16x8*)(wbb + (wn * 64 + 2 * 16 + fr) * LDK + fq * 8);
            bf16x8 wF3 = *(const bf16x8*)(wbb + (wn * 64 + 3 * 16 + fr) * LDK + fq * 8);
            bf16x8 aF[6];
            #pragma unroll
            for (int ms = 0; ms < 6; ++ms)
                aF[ms] = *(const bf16x8*)(bb + (wg * 96 + ms * 16 + fr) * LDK + fq * 8);
            #pragma unroll
            for (int ms = 0; ms < 6; ++ms) {
                if (rem > ms * 16) {
                    acc[ms][0] = __builtin_amdgcn_mfma_f32_16x16x32_bf16(aF[ms], wF0, acc[ms][0], 0, 0, 0);
                    acc[ms][1] = __builtin_amdgcn_mfma_f32_16x16x32_bf16(aF[ms], wF1, acc[ms][1], 0, 0, 0);
                    acc[ms][2] = __builtin_amdgcn_mfma_f32_16x16x32_bf16(aF[ms], wF2, acc[ms][2], 0, 0, 0);
                    acc[ms][3] = __builtin_amdgcn_mfma_f32_16x16x32_bf16(aF[ms], wF3, acc[ms][3], 0, 0, 0);
                }
            }
        };

        // prologue
        LOAD_WE(0);
        LOAD_WO(1);
        LOAD_A(0);
        WRITE_WE(0);
        WRITE_A(0);
        LOAD_A(1);
        asm volatile("s_waitcnt lgkmcnt(0)" ::: "memory");
        __builtin_amdgcn_s_barrier();

        for (int s = 0; s < NS; s += 2) {
            if (s + 2 < NS) LOAD_WE(s + 2);
            STEP(smem);
            WRITE_WO(s + 1);
            WRITE_A(s + 1);
            if (s + 2 < NS) LOAD_A(s + 2);
            asm volatile("s_waitcnt lgkmcnt(0)" ::: "memory");
            __builtin_amdgcn_s_barrier();
            if (s + 3 < NS) LOAD_WO(s + 3);
            STEP(smem + 12800);
            if (s + 2 < NS) { WRITE_WE(s + 2); WRITE_A(s + 2); }
            if (s + 3 < NS) LOAD_A(s + 3);
            asm volatile("s_waitcnt lgkmcnt(0)" ::: "memory");
            __builtin_amdgcn_s_barrier();
        }

        // epilogue
        #pragma unroll
        for (int ms = 0; ms < 6; ++ms) {
            #pragma unroll
            for (int i = 0; i < 4; ++i) {
                int lrow = wg * 96 + ms * 16 + fq * 4 + i;
                int grow = m0 + lrow;
                if (grow < nrows) {
                    int p = rows[r0 + grow];
                    if (USE_ATOMIC) {
                        float w = wts[p];
                        float* orow = outp + (size_t)(p >> 3) * HID + n0 + wn * 64;
                        #pragma unroll
                        for (int ns = 0; ns < 4; ++ns)
                            atomicAdd(orow + ns * 16 + fr, acc[ms][ns][i] * w);
                    } else {
                        // plain coalesced stores to per-pair buffer (no atomics)
                        float* orow = outp + (size_t)p * HID + n0 + wn * 64;
                        #pragma unroll
                        for (int ns = 0; ns < 4; ++ns)
                            orow[ns * 16 + fr] = acc[ms][ns][i];
                    }
                }
            }
        }
        __syncthreads();
    }
}

// ---------------------------------------------------------------------------
// combine: out[t] = sum_j wts[t*8+j] * pout[t*8+j]  (fully coalesced)
// ---------------------------------------------------------------------------
__global__ __launch_bounds__(256) void combine_kernel(
    const float* __restrict__ pout, const float* __restrict__ wts,
    float* __restrict__ out)
{
    const int idx = blockIdx.x * 256 + threadIdx.x;   // one f32x4 per thread
    const int t   = idx >> 9;                         // HID/4 = 512 chunks/token
    const int c4  = (idx & 511) * 4;

    const float* w8 = wts + t * TOPK;
    const float* pr = pout + (size_t)t * TOPK * HID + c4;
    f32x4 s = (f32x4){0.f, 0.f, 0.f, 0.f};
    #pragma unroll
    for (int j = 0; j < TOPK; ++j) {
        f32x4 v = *(const f32x4*)(pr + (size_t)j * HID);
        float w = w8[j];
        s[0] += w * v[0]; s[1] += w * v[1]; s[2] += w * v[2]; s[3] += w * v[3];
    }
    *(f32x4*)(out + (size_t)t * HID + c4) = s;
}

// ---------------------------------------------------------------------------
extern "C" void kernel_launch(void* const* d_in, const int* in_sizes, int n_in,
                              void* d_out, int out_size, void* d_ws, size_t ws_size,
                              hipStream_t stream)
{
    const float* hs = (const float*)d_in[0];   // [1024, 2048]
    const float* rw = (const float*)d_in[1];   // [2048, 64]
    const float* gw = (const float*)d_in[2];   // [64, 2048, 768]
    const float* uw = (const float*)d_in[3];   // [64, 2048, 768]
    const float* dw = (const float*)d_in[4];   // [64, 768, 2048]
    float* out = (float*)d_out;                // [1024, 2048]

    char* ws = (char*)d_ws;
    int*   sel     = (int*)(ws);                         // 8192 ints
    float* wts     = (float*)(ws + 32768);               // 8192 floats
    int*   offsets = (int*)(ws + 65792);                 // 65
    int*   rows    = (int*)(ws + 66560);                 // 8192
    unsigned short* xb = (unsigned short*)(ws + 99328);            // 4 MB bf16
    unsigned short* hb = (unsigned short*)(ws + 99328 + 4194304);  // 12.6 MB bf16
    float* pout = (float*)(ws + 99328 + 4194304 + 12582912);       // 67 MB f32
    const size_t need = 99328ull + 4194304 + 12582912 + (size_t)NPAIR * HID * 4;

    router_topk_kernel<<<T_TOKENS / 4, 256, 0, stream>>>(hs, rw, sel, wts, xb);
    route_kernel<<<1, 1024, 0, stream>>>(sel, offsets, rows);
    gateup_kernel<<<768, 512, 0, stream>>>(xb, gw, uw, offsets, rows, hb);

    if (ws_size >= need) {
        // atomic-free path: down -> per-pair buffer, then weighted combine
        down_kernel_t<0><<<1024, 256, 0, stream>>>(hb, dw, offsets, rows, wts, pout);
        combine_kernel<<<T_TOKENS * HID / 4 / 256, 256, 0, stream>>>(pout, wts, out);
    } else {
        hipMemsetAsync(out, 0, (size_t)T_TOKENS * HID * sizeof(float), stream);
        down_kernel_t<1><<<1024, 256, 0, stream>>>(hb, dw, offsets, rows, wts, out);
    }
}